// Round 4
// baseline (80298.389 us; speedup 1.0000x reference)
//
#include <hip/hip_runtime.h>
#include <math.h>

// ---------------------------------------------------------------------------
// LSTM-CRF (B=64,T=512,E=256,H=256,K=32,V=50000), all f32.
// Recurrence sync: relaxed agent-scope atomics ONLY (cache-bypassing, no
// acquire/release -> no per-poll L2 invalidate storms).
// Layouts:
//   xg  [dir][ls(64)][gate(1024)][b]   (per-chunk, reused)
//   out [t][unit(512)][b]
//   hbuf[d][parity][batch(64)][unit(256)]  (transposed for row-wise staging)
//   em  [t][b][tag(32)]
// ---------------------------------------------------------------------------

constexpr int TLEN = 512, CS = 64, NCH = 8;

constexpr size_t O_OUT0 = 0;
constexpr size_t N_OUT  = (size_t)TLEN * 512 * 64;          // 16,777,216
constexpr size_t O_OUT1 = O_OUT0 + N_OUT;
constexpr size_t O_XG   = O_OUT1 + N_OUT;
constexpr size_t N_XG   = (size_t)2 * CS * 1024 * 64;       // 8,388,608
constexpr size_t O_EM   = O_XG + N_XG;
constexpr size_t N_EM   = (size_t)TLEN * 64 * 32;           // 1,048,576
constexpr size_t O_HBUF = O_EM + N_EM;                      // [2L][2d][2p][64][256]
constexpr size_t N_HBUF = (size_t)2 * 2 * 2 * 64 * 256;     // 131,072
constexpr size_t O_CST  = O_HBUF + N_HBUF;                  // [2L][2d][256][64]
constexpr size_t N_CST  = (size_t)2 * 2 * 256 * 64;         // 65,536
constexpr size_t O_FLG  = O_CST + N_CST;                    // [2L][2d][512][64] ints
constexpr size_t N_FLG  = (size_t)2 * 2 * 512 * 64;         // 131,072
constexpr size_t WS_FLOATS = O_FLG + N_FLG;                 // ~173 MB

// ---------------------------------------------------------------------- init
__global__ __launch_bounds__(256) void initz(float* hbuf, float* cst, int* flg,
                                             float* dout) {
  int i = blockIdx.x * 256 + threadIdx.x;  // grid 512 -> 131072 threads
  if (i < (int)N_HBUF) hbuf[i] = 0.f;
  if (i < (int)N_CST) cst[i] = 0.f;
  if (i < (int)N_FLG) flg[i] = 0;
  if (i == 0) dout[0] = 0.f;
}

__global__ void ws_too_small_k(float* dout, int n) {
  int i = blockIdx.x * 256 + threadIdx.x;
  if (i < n) dout[i] = 1e30f;  // clean diagnostic failure, no fault
}

// ------------------------------------------------------------------- GEMM
// xg[d][ls][n][b] = A_row(t(b,ls)) . W[n] + bias[n]  for steps s in [s0,s0+CS)
// AMODE 0: A = emb table, rows gathered via ids (layer 0, K=256).
// AMODE 1: A = out0 [t][512][b] (layer 1, K=512).
template <int KTOT, int AMODE>
__global__ __launch_bounds__(256)
void gemm_xg(const float* __restrict__ A, const int* __restrict__ ids,
             const float* __restrict__ Wf, const float* __restrict__ Wb,
             const float* __restrict__ bf, const float* __restrict__ bb,
             float* __restrict__ xg, int s0) {
  constexpr int BK = 16;
  __shared__ float As[BK][132];
  __shared__ float Bs[BK][132];
  const int tid = threadIdx.x;
  const int m0 = blockIdx.x * 128, n0 = blockIdx.y * 128, d = blockIdx.z;
  const float* W = d ? Wb : Wf;
  const float* bias = d ? bb : bf;
  const int mg = tid & 15, ng = tid >> 4;
  const int rb = tid >> 2;            // 0..63
  const int kq = (tid & 3) << 2;      // 0,4,8,12
  const int ls0 = m0 >> 6;            // first local step of this M-tile

  int arow[2];  // AMODE0: emb row ids ; AMODE1: time t
  #pragma unroll
  for (int p = 0; p < 2; ++p) {
    int s = s0 + ls0 + p;
    int t = d ? (TLEN - 1 - s) : s;
    arow[p] = (AMODE == 0) ? ids[rb * TLEN + t] : t;
  }

  float acc[8][8];
  #pragma unroll
  for (int i = 0; i < 8; ++i)
    #pragma unroll
    for (int j = 0; j < 8; ++j) acc[i][j] = 0.f;

  for (int kt = 0; kt < KTOT; kt += BK) {
    if (AMODE == 0) {
      #pragma unroll
      for (int p = 0; p < 2; ++p) {
        float4 v = *reinterpret_cast<const float4*>(A + (size_t)arow[p] * KTOT + kt + kq);
        int r = p * 64 + rb;
        As[kq + 0][r] = v.x; As[kq + 1][r] = v.y;
        As[kq + 2][r] = v.z; As[kq + 3][r] = v.w;
      }
    } else {
      const int b = tid & 63;
      #pragma unroll
      for (int p = 0; p < 8; ++p) {
        int flat = p * 4 + (tid >> 6);     // 0..31 = tl(2) x kk(16)
        int tl = flat >> 4, kk = flat & 15;
        As[kk][tl * 64 + b] = A[((size_t)arow[tl] * 512 + kt + kk) * 64 + b];
      }
    }
    #pragma unroll
    for (int p = 0; p < 2; ++p) {
      int r = p * 64 + rb;
      float4 v = *reinterpret_cast<const float4*>(W + (size_t)(n0 + r) * KTOT + kt + kq);
      Bs[kq + 0][r] = v.x; Bs[kq + 1][r] = v.y;
      Bs[kq + 2][r] = v.z; Bs[kq + 3][r] = v.w;
    }
    __syncthreads();
    #pragma unroll
    for (int k = 0; k < BK; ++k) {
      float a[8], w[8];
      #pragma unroll
      for (int i = 0; i < 8; ++i) a[i] = As[k][i * 16 + mg];
      float4 w0 = *reinterpret_cast<const float4*>(&Bs[k][ng * 8]);
      float4 w1 = *reinterpret_cast<const float4*>(&Bs[k][ng * 8 + 4]);
      w[0] = w0.x; w[1] = w0.y; w[2] = w0.z; w[3] = w0.w;
      w[4] = w1.x; w[5] = w1.y; w[6] = w1.z; w[7] = w1.w;
      #pragma unroll
      for (int i = 0; i < 8; ++i)
        #pragma unroll
        for (int j = 0; j < 8; ++j) acc[i][j] += a[i] * w[j];
    }
    __syncthreads();
  }
  #pragma unroll
  for (int j = 0; j < 8; ++j) {
    const int n = n0 + ng * 8 + j;
    const float bv = bias[n];
    #pragma unroll
    for (int i = 0; i < 8; ++i) {
      const int ml = i * 16 + mg;
      const int ls = ls0 + (ml >> 6);
      const int b = ml & 63;
      xg[(((size_t)d * CS + ls) * 1024 + n) * 64 + b] = acc[i][j] + bv;
    }
  }
}

// ------------------------------------------------------------- LSTM recurrence
// grid = 128: dir = bid>>6, group g = bid&63 (4 units, one per wave), lane=batch.
// h handoff: relaxed agent atomics (cache-bypassing), per-(step,group) flags.
static __device__ __forceinline__ float sigm(float x) { return 1.f / (1.f + expf(-x)); }

__global__ __launch_bounds__(256)
void lstm_rec(const float* __restrict__ xg, const float* whhf,
              const float* whhb, float* __restrict__ out,
              float* hbuf /*[2d][2p][64][256]*/,
              float* cst /*[2d][256][64]*/,
              int* flg /*[2d][512][64]*/, int s0) {
  const int d = blockIdx.x >> 6;
  const int g = blockIdx.x & 63;
  const int tid = threadIdx.x;
  const int lane = tid & 63;
  const int wv = __builtin_amdgcn_readfirstlane(tid >> 6);
  const int u = g * 4 + wv;
  const float* whh = d ? whhb : whhf;
  const float* wri = whh + (size_t)u * 256;
  const float* wrf = whh + (size_t)(256 + u) * 256;
  const float* wrg = whh + (size_t)(512 + u) * 256;
  const float* wro = whh + (size_t)(768 + u) * 256;
  float* hb = hbuf + (size_t)d * 2 * 16384;
  float* cs = cst + (size_t)d * 16384;
  int* fl = flg + (size_t)d * TLEN * 64;
  __shared__ float hs[64 * 256];  // [b][k], 16B-granule XOR-swizzled, 64 KB
  float c = cs[(size_t)u * 64 + lane];
  const int swz = lane & 7;

  for (int ls = 0; ls < CS; ++ls) {
    const int s = s0 + ls;
    const int t = d ? (TLEN - 1 - s) : s;
    if (s > 0) {
      while (!__all(__hip_atomic_load(&fl[(size_t)(s - 1) * 64 + lane],
                                      __ATOMIC_RELAXED, __HIP_MEMORY_SCOPE_AGENT) != 0)) {}
      asm volatile("" ::: "memory");
    }
    // ---- stage h_{s-1} (slot s&1): coalesced 8B bypass loads -> swizzled LDS
    {
      const unsigned long long* src =
          reinterpret_cast<const unsigned long long*>(hb + (size_t)(s & 1) * 16384)
          + (size_t)wv * 2048 + lane;
      #pragma unroll
      for (int j = 0; j < 32; ++j) {
        unsigned long long v = __hip_atomic_load(src + j * 64, __ATOMIC_RELAXED,
                                                 __HIP_MEMORY_SCOPE_AGENT);
        const int b = wv * 16 + (j >> 1);
        const int k = ((j & 1) << 7) + lane * 2;
        const int phys = (k >> 2) ^ (b & 7);
        *reinterpret_cast<unsigned long long*>(
            reinterpret_cast<char*>(hs) + b * 1024 + phys * 16 + ((lane & 1) << 3)) = v;
      }
    }
    __syncthreads();
    const size_t xb = ((size_t)d * CS + ls) * 1024;
    float xi = xg[(xb + u) * 64 + lane];
    float xf = xg[(xb + 256 + u) * 64 + lane];
    float xgv = xg[(xb + 512 + u) * 64 + lane];
    float xo = xg[(xb + 768 + u) * 64 + lane];
    float ai = 0.f, af = 0.f, ag = 0.f, ao = 0.f;
    const char* rowp = reinterpret_cast<const char*>(hs) + lane * 1024;
    #pragma unroll
    for (int j = 0; j < 64; ++j) {
      float4 h4 = *reinterpret_cast<const float4*>(rowp + ((j ^ swz) << 4));
      const int k = 4 * j;  // logical k (weights wave-uniform -> scalar loads)
      ai = fmaf(h4.x, wri[k], fmaf(h4.y, wri[k + 1], fmaf(h4.z, wri[k + 2], fmaf(h4.w, wri[k + 3], ai))));
      af = fmaf(h4.x, wrf[k], fmaf(h4.y, wrf[k + 1], fmaf(h4.z, wrf[k + 2], fmaf(h4.w, wrf[k + 3], af))));
      ag = fmaf(h4.x, wrg[k], fmaf(h4.y, wrg[k + 1], fmaf(h4.z, wrg[k + 2], fmaf(h4.w, wrg[k + 3], ag))));
      ao = fmaf(h4.x, wro[k], fmaf(h4.y, wro[k + 1], fmaf(h4.z, wro[k + 2], fmaf(h4.w, wro[k + 3], ao))));
    }
    const float gi = sigm(xi + ai), gf = sigm(xf + af);
    const float gc = tanhf(xgv + ag), go = sigm(xo + ao);
    c = gf * c + gi * gc;
    const float h = go * tanhf(c);
    // bypassing store of h (transposed [batch][unit]); normal store of out
    __hip_atomic_store(hb + (size_t)((s & 1) ^ 1) * 16384 + (size_t)lane * 256 + u,
                       h, __ATOMIC_RELAXED, __HIP_MEMORY_SCOPE_AGENT);
    out[((size_t)t * 512 + (size_t)d * 256 + u) * 64 + lane] = h;
    asm volatile("s_waitcnt vmcnt(0)" ::: "memory");  // h at coherence point
    __syncthreads();                                   // all 4 waves drained
    if (tid == 0)
      __hip_atomic_store(&fl[(size_t)s * 64 + g], 1, __ATOMIC_RELAXED,
                         __HIP_MEMORY_SCOPE_AGENT);
  }
  cs[(size_t)u * 64 + lane] = c;
}

// ------------------------------------------------------------ emission proj
// em[t][b][n] = sum_k out1[t][k][b]*w_out[n][k] + b_out[n]
__global__ __launch_bounds__(256)
void emproj(const float* __restrict__ h1, const float* __restrict__ wo,
            const float* __restrict__ bo, float* __restrict__ em) {
  __shared__ float wsm[32 * 512];  // 64 KB
  const int t = blockIdx.x;
  for (int i = threadIdx.x; i < 32 * 512 / 4; i += 256)
    reinterpret_cast<float4*>(wsm)[i] = reinterpret_cast<const float4*>(wo)[i];
  __syncthreads();
  const int b = threadIdx.x & 63, tg = threadIdx.x >> 6;  // tg: 8 tags each
  float acc[8] = {0, 0, 0, 0, 0, 0, 0, 0};
  const float* hbp = h1 + (size_t)t * 512 * 64 + b;
  #pragma unroll 8
  for (int k = 0; k < 512; ++k) {
    float hv = hbp[(size_t)k * 64];
    #pragma unroll
    for (int j = 0; j < 8; ++j) acc[j] += hv * wsm[(tg * 8 + j) * 512 + k];
  }
  #pragma unroll
  for (int j = 0; j < 8; ++j) {
    int n = tg * 8 + j;
    em[((size_t)t * 64 + b) * 32 + n] = acc[j] + bo[n];
  }
}

// ------------------------------------------------------- CRF loss + Viterbi
// grid=128, 64 thr: blocks 0..63 loss(batch b), 64..127 viterbi(batch b).
__global__ __launch_bounds__(64)
void crf_k(const float* __restrict__ em, const int* __restrict__ labels,
           const float* __restrict__ cs, const float* __restrict__ ce,
           const float* __restrict__ ct, float* __restrict__ dout) {
  __shared__ float trs[32 * 32];
  __shared__ float as_[32];
  __shared__ unsigned char bp[511 * 32];
  const int b = blockIdx.x & 63;
  const bool vit = blockIdx.x >= 64;
  const int lane = threadIdx.x;
  for (int i = lane; i < 1024; i += 64) trs[i] = ct[i];
  __syncthreads();
  const int j = lane & 31, half = lane >> 5, i0 = half * 16;

  if (!vit) {
    float part = 0.f;
    for (int tt = lane; tt < TLEN; tt += 64) {
      int lab = labels[b * TLEN + tt];
      part += em[((size_t)tt * 64 + b) * 32 + lab];
      if (tt) part += trs[labels[b * TLEN + tt - 1] * 32 + lab];
    }
    for (int o = 32; o > 0; o >>= 1) part += __shfl_down(part, o);
    float num = part;  // lane 0
    if (lane == 0) num += cs[labels[b * TLEN]] + ce[labels[b * TLEN + TLEN - 1]];
    if (lane < 32) as_[j] = cs[j] + em[(size_t)b * 32 + j];
    __syncthreads();
    for (int t = 1; t < TLEN; ++t) {
      float m = -1e30f;
      #pragma unroll
      for (int ii = 0; ii < 16; ++ii)
        m = fmaxf(m, as_[i0 + ii] + trs[(i0 + ii) * 32 + j]);
      float s = 0.f;
      #pragma unroll
      for (int ii = 0; ii < 16; ++ii)
        s += expf(as_[i0 + ii] + trs[(i0 + ii) * 32 + j] - m);
      float om = __shfl_xor(m, 32), os = __shfl_xor(s, 32);
      float M = fmaxf(m, om);
      s = s * expf(m - M) + os * expf(om - M);
      float na = M + logf(s) + em[((size_t)t * 64 + b) * 32 + j];
      __syncthreads();
      if (half == 0) as_[j] = na;
      __syncthreads();
    }
    float v = (lane < 32) ? as_[j] + ce[j] : -1e30f;
    float m = v;
    for (int o = 32; o > 0; o >>= 1) m = fmaxf(m, __shfl_xor(m, o));
    float s = (lane < 32) ? expf(v - m) : 0.f;
    for (int o = 32; o > 0; o >>= 1) s += __shfl_xor(s, o);
    if (lane == 0) atomicAdd(dout, -(num - (m + logf(s))));
  } else {
    if (lane < 32) as_[j] = cs[j] + em[(size_t)b * 32 + j];
    __syncthreads();
    for (int t = 1; t < TLEN; ++t) {
      float m = -1e30f; int am = 0;
      #pragma unroll
      for (int ii = 0; ii < 16; ++ii) {
        float v = as_[i0 + ii] + trs[(i0 + ii) * 32 + j];
        if (v > m) { m = v; am = i0 + ii; }
      }
      float om = __shfl_xor(m, 32); int oam = __shfl_xor(am, 32);
      float M; int AM;
      if (half == 0) { if (om > m) { M = om; AM = oam; } else { M = m; AM = am; } }
      else           { if (m > om) { M = m; AM = am; } else { M = om; AM = oam; } }
      float na = M + em[((size_t)t * 64 + b) * 32 + j];
      if (half == 0) bp[(t - 1) * 32 + j] = (unsigned char)AM;
      __syncthreads();
      if (half == 0) as_[j] = na;
      __syncthreads();
    }
    float v = (lane < 32) ? as_[j] + ce[j] : -1e30f;
    int aj = (lane < 32) ? j : 0;
    #pragma unroll
    for (int o = 1; o < 64; o <<= 1) {
      float ov = __shfl_xor(v, o); int oa = __shfl_xor(aj, o);
      if (ov > v || (ov == v && oa < aj)) { v = ov; aj = oa; }
    }
    if (lane == 0) {
      int cur = aj;
      dout[1 + b * TLEN + TLEN - 1] = (float)cur;
      for (int t = TLEN - 1; t >= 1; --t) {
        cur = bp[(t - 1) * 32 + cur];
        dout[1 + b * TLEN + t - 1] = (float)cur;
      }
    }
  }
}

// --------------------------------------------------------------------- launch
extern "C" void kernel_launch(void* const* d_in, const int* in_sizes, int n_in,
                              void* d_out, int out_size, void* d_ws, size_t ws_size,
                              hipStream_t stream) {
  (void)in_sizes; (void)n_in;
  float* dout = (float*)d_out;
  if (ws_size < WS_FLOATS * sizeof(float)) {  // diagnostic, not a fault
    ws_too_small_k<<<(out_size + 255) / 256, 256, 0, stream>>>(dout, out_size);
    return;
  }
  const int* ids    = (const int*)d_in[0];
  const int* labels = (const int*)d_in[1];
  const float* emb  = (const float*)d_in[3];
  const float* wih0f = (const float*)d_in[4],  *whh0f = (const float*)d_in[5],  *b0f = (const float*)d_in[6];
  const float* wih0b = (const float*)d_in[7],  *whh0b = (const float*)d_in[8],  *b0b = (const float*)d_in[9];
  const float* wih1f = (const float*)d_in[10], *whh1f = (const float*)d_in[11], *b1f = (const float*)d_in[12];
  const float* wih1b = (const float*)d_in[13], *whh1b = (const float*)d_in[14], *b1b = (const float*)d_in[15];
  const float* w_out = (const float*)d_in[16], *b_out = (const float*)d_in[17];
  const float* c_s = (const float*)d_in[18], *c_e = (const float*)d_in[19], *c_t = (const float*)d_in[20];
  float* ws   = (float*)d_ws;
  float* out0 = ws + O_OUT0;
  float* out1 = ws + O_OUT1;
  float* xg   = ws + O_XG;
  float* em   = ws + O_EM;
  float* hbuf = ws + O_HBUF;
  float* cst  = ws + O_CST;
  int*   flg  = (int*)(ws + O_FLG);

  initz<<<512, 256, 0, stream>>>(hbuf, cst, flg, dout);
  for (int k = 0; k < NCH; ++k) {
    gemm_xg<256, 0><<<dim3(32, 8, 2), 256, 0, stream>>>(emb, ids, wih0f, wih0b, b0f, b0b, xg, k * CS);
    lstm_rec<<<128, 256, 0, stream>>>(xg, whh0f, whh0b, out0, hbuf, cst, flg, k * CS);
  }
  for (int k = 0; k < NCH; ++k) {
    gemm_xg<512, 1><<<dim3(32, 8, 2), 256, 0, stream>>>(out0, nullptr, wih1f, wih1b, b1f, b1b, xg, k * CS);
    lstm_rec<<<128, 256, 0, stream>>>(xg, whh1f, whh1b, out1,
                                      hbuf + (size_t)2 * 16384,
                                      cst + (size_t)2 * 16384 / 2 * 2,
                                      flg + (size_t)2 * TLEN * 64, k * CS);
  }
  emproj<<<512, 256, 0, stream>>>(out1, w_out, b_out, em);
  crf_k<<<128, 64, 0, stream>>>(em, labels, c_s, c_e, c_t, dout);
}

// Round 5
// 17006.699 us; speedup vs baseline: 4.7216x; 4.7216x over previous
//
#include <hip/hip_runtime.h>
#include <math.h>

// ---------------------------------------------------------------------------
// LSTM-CRF (B=64,T=512,E=256,H=256,K=32,V=50000), all f32.
// Recurrence is BATCH-PARALLEL: WG = (dir, batch-pair). Batches are
// independent sequences -> zero inter-WG sync. h lives in LDS, c in regs,
// weights stream from L2 as coalesced float4 (wQ[k][u][4] layout).
// Layouts (row-major everywhere):
//   xg  [d*4096 + ls*64 + b][1024]   (per-chunk, reused; em aliases this)
//   out [t*64 + b][512]              (col = d*256 + u)
//   em  [t*64 + b][32]
//   wq  [d][k(256)][u(256)][g(4)]    (per-layer, rebuilt between layers)
// ---------------------------------------------------------------------------

constexpr int TLEN = 512, CS = 64, NCH = 8;

constexpr size_t N_OUT  = (size_t)TLEN * 64 * 512;      // 16,777,216
constexpr size_t O_OUT0 = 0;
constexpr size_t O_OUT1 = N_OUT;
constexpr size_t O_XG   = 2 * N_OUT;
constexpr size_t N_XG   = (size_t)2 * CS * 64 * 1024;   // 8,388,608
constexpr size_t O_EM   = O_XG;                         // alias: xg dead when em live
constexpr size_t O_WQ   = O_XG + N_XG;
constexpr size_t N_WQ   = (size_t)2 * 256 * 256 * 4;    // 524,288 (one layer)
constexpr size_t O_CST  = O_WQ + N_WQ;
constexpr size_t N_CST  = (size_t)2 * 2 * 64 * 256;     // 65,536 (2 layers)
constexpr size_t WS_FLOATS = O_CST + N_CST;             // 42,532,864 ~ 170.1 MB

// ---------------------------------------------------------------------- init
__global__ void initz(float* dout) { if (threadIdx.x == 0) dout[0] = 0.f; }

__global__ void ws_too_small_k(float* dout, int n) {
  int i = blockIdx.x * 256 + threadIdx.x;
  if (i < n) dout[i] = 1e30f;  // clean diagnostic failure, no fault
}

// ------------------------------------------------------------------ prep_w
// wq[d][k][u][g] = whh_d[(g*256+u)*256 + k]; one float4 store per thread.
__global__ __launch_bounds__(256)
void prep_w(const float* __restrict__ whhf, const float* __restrict__ whhb,
            float* __restrict__ wq) {
  const int k = blockIdx.x & 255, d = blockIdx.x >> 8, u = threadIdx.x;
  const float* W = d ? whhb : whhf;
  float4 v;
  v.x = W[(size_t)(0   + u) * 256 + k];
  v.y = W[(size_t)(256 + u) * 256 + k];
  v.z = W[(size_t)(512 + u) * 256 + k];
  v.w = W[(size_t)(768 + u) * 256 + k];
  reinterpret_cast<float4*>(wq)[(size_t)d * 65536 + k * 256 + u] = v;
}

// -------------------------------------------------------------------- GEMM
// C = A @ W^T + bias, C row-major.
// MODE 0: A-rows gathered from emb via ids (layer-0 xg, K=256, BN=128)
// MODE 1: A = out0 row-major, rows t*64+b (layer-1 xg, K=512, BN=128)
// MODE 2: A = out1 row-major, rows = m  (emissions, K=512, BN=32)
template <int KTOT, int BN, int MODE>
__global__ __launch_bounds__(256)
void gemm_k(const float* __restrict__ A, const int* __restrict__ ids,
            const float* __restrict__ Wf, const float* __restrict__ Wb,
            const float* __restrict__ bf, const float* __restrict__ bb,
            float* __restrict__ C, int s0) {
  constexpr int BK = 16;
  constexpr int NC = (BN == 128) ? 8 : 2;  // cols per thread
  __shared__ float As[BK][132];
  __shared__ float Bs[BK][BN + 4];
  const int tid = threadIdx.x;
  const int m0 = blockIdx.x * 128, n0 = blockIdx.y * BN, d = blockIdx.z;
  const float* W = (MODE < 2 && d) ? Wb : Wf;
  const float* bias = (MODE < 2 && d) ? bb : bf;
  const int mg = tid & 15, ng = tid >> 4;
  const int rb = tid >> 2;            // 0..63
  const int kq = (tid & 3) << 2;      // 0,4,8,12

  int arow[2];
  #pragma unroll
  for (int p = 0; p < 2; ++p) {
    if (MODE == 2) {
      arow[p] = m0 + p * 64 + rb;
    } else {
      int s = s0 + (m0 >> 6) + p;
      int t = d ? (TLEN - 1 - s) : s;
      arow[p] = (MODE == 0) ? ids[rb * TLEN + t] : (t * 64 + rb);
    }
  }

  float acc[8][NC];
  #pragma unroll
  for (int i = 0; i < 8; ++i)
    #pragma unroll
    for (int jj = 0; jj < NC; ++jj) acc[i][jj] = 0.f;

  for (int kt = 0; kt < KTOT; kt += BK) {
    #pragma unroll
    for (int p = 0; p < 2; ++p) {
      float4 v = *reinterpret_cast<const float4*>(A + (size_t)arow[p] * KTOT + kt + kq);
      int r = p * 64 + rb;
      As[kq + 0][r] = v.x; As[kq + 1][r] = v.y;
      As[kq + 2][r] = v.z; As[kq + 3][r] = v.w;
    }
    #pragma unroll
    for (int p = 0; p < 2; ++p) {
      int r = p * 64 + rb;
      if (BN == 128 || (p == 0 && rb < BN)) {
        float4 v = *reinterpret_cast<const float4*>(W + (size_t)(n0 + r) * KTOT + kt + kq);
        Bs[kq + 0][r] = v.x; Bs[kq + 1][r] = v.y;
        Bs[kq + 2][r] = v.z; Bs[kq + 3][r] = v.w;
      }
    }
    __syncthreads();
    #pragma unroll
    for (int k = 0; k < BK; ++k) {
      float a[8];
      #pragma unroll
      for (int i = 0; i < 8; ++i) a[i] = As[k][i * 16 + mg];
      if (BN == 128) {
        float w[8];
        float4 w0 = *reinterpret_cast<const float4*>(&Bs[k][ng * 8]);
        float4 w1 = *reinterpret_cast<const float4*>(&Bs[k][ng * 8 + 4]);
        w[0] = w0.x; w[1] = w0.y; w[2] = w0.z; w[3] = w0.w;
        w[4] = w1.x; w[5] = w1.y; w[6] = w1.z; w[7] = w1.w;
        #pragma unroll
        for (int i = 0; i < 8; ++i)
          #pragma unroll
          for (int jj = 0; jj < 8; ++jj) acc[i][jj] += a[i] * w[jj];
      } else {
        float w0 = Bs[k][ng * 2], w1 = Bs[k][ng * 2 + 1];
        #pragma unroll
        for (int i = 0; i < 8; ++i) {
          acc[i][0] += a[i] * w0;
          acc[i][1] += a[i] * w1;
        }
      }
    }
    __syncthreads();
  }

  if (BN == 128) {
    float bv[8];
    #pragma unroll
    for (int jj = 0; jj < 8; ++jj) bv[jj] = bias[n0 + ng * 8 + jj];
    #pragma unroll
    for (int i = 0; i < 8; ++i) {
      const int ml = i * 16 + mg;
      float* cp = C + ((size_t)d * 4096 + m0 + ml) * 1024 + n0 + ng * 8;
      float4 o0, o1;
      o0.x = acc[i][0] + bv[0]; o0.y = acc[i][1] + bv[1];
      o0.z = acc[i][2] + bv[2]; o0.w = acc[i][3] + bv[3];
      o1.x = acc[i][4] + bv[4]; o1.y = acc[i][5] + bv[5];
      o1.z = acc[i][6] + bv[6]; o1.w = acc[i][7] + bv[7];
      reinterpret_cast<float4*>(cp)[0] = o0;
      reinterpret_cast<float4*>(cp)[1] = o1;
    }
  } else {
    const float b0 = bias[ng * 2], b1 = bias[ng * 2 + 1];
    #pragma unroll
    for (int i = 0; i < 8; ++i) {
      const int ml = i * 16 + mg;
      float* cp = C + (size_t)(m0 + ml) * 32 + ng * 2;
      cp[0] = acc[i][0] + b0;
      cp[1] = acc[i][1] + b1;
    }
  }
}

// ------------------------------------------------------------- LSTM recurrence
// grid = 64 WGs x 512 thr: d = bid>>5, batch-pair = bid&31; thread = (u, j).
// Fully private per WG: h double-buffered in LDS, c in regs, no global sync.
static __device__ __forceinline__ float sigm(float x) { return 1.f / (1.f + expf(-x)); }

__global__ __launch_bounds__(512)
void lstm_bp(const float* __restrict__ xg, const float* __restrict__ wq,
             float* __restrict__ out, float* __restrict__ cst, int s0) {
  const int d = blockIdx.x >> 5;
  const int bp = blockIdx.x & 31;
  const int u = threadIdx.x & 255;
  const int j = threadIdx.x >> 8;
  const int b = bp * 2 + j;
  const float4* wp = reinterpret_cast<const float4*>(wq) + (size_t)d * 65536 + u;
  float* cptr = cst + ((size_t)d * 64 + b) * 256 + u;
  __shared__ float hs[2][2][256];
  float c;
  if (s0 == 0) {
    c = 0.f;
    hs[0][j][u] = 0.f;
  } else {
    c = *cptr;
    const int tp = d ? (TLEN - s0) : (s0 - 1);
    hs[0][j][u] = out[((size_t)tp * 64 + b) * 512 + d * 256 + u];
  }
  __syncthreads();
  int p = 0;
  for (int ls = 0; ls < CS; ++ls) {
    const int s = s0 + ls;
    const int t = d ? (TLEN - 1 - s) : s;
    const size_t xb = (((size_t)d * CS + ls) * 64 + b) * 1024;
    const float xi = xg[xb + u];
    const float xf = xg[xb + 256 + u];
    const float xgv = xg[xb + 512 + u];
    const float xo = xg[xb + 768 + u];
    float ai = 0.f, af = 0.f, ag = 0.f, ao = 0.f;
    const float4* hp = reinterpret_cast<const float4*>(&hs[p][j][0]);
    #pragma unroll 4
    for (int k4 = 0; k4 < 64; ++k4) {
      const float4 h4 = hp[k4];
      const float4 w0 = wp[(k4 * 4 + 0) * 256];
      const float4 w1 = wp[(k4 * 4 + 1) * 256];
      const float4 w2 = wp[(k4 * 4 + 2) * 256];
      const float4 w3 = wp[(k4 * 4 + 3) * 256];
      ai = fmaf(h4.x, w0.x, ai); af = fmaf(h4.x, w0.y, af);
      ag = fmaf(h4.x, w0.z, ag); ao = fmaf(h4.x, w0.w, ao);
      ai = fmaf(h4.y, w1.x, ai); af = fmaf(h4.y, w1.y, af);
      ag = fmaf(h4.y, w1.z, ag); ao = fmaf(h4.y, w1.w, ao);
      ai = fmaf(h4.z, w2.x, ai); af = fmaf(h4.z, w2.y, af);
      ag = fmaf(h4.z, w2.z, ag); ao = fmaf(h4.z, w2.w, ao);
      ai = fmaf(h4.w, w3.x, ai); af = fmaf(h4.w, w3.y, af);
      ag = fmaf(h4.w, w3.z, ag); ao = fmaf(h4.w, w3.w, ao);
    }
    const float gi = sigm(xi + ai), gf = sigm(xf + af);
    const float gc = tanhf(xgv + ag), go = sigm(xo + ao);
    c = gf * c + gi * gc;
    const float h = go * tanhf(c);
    hs[p ^ 1][j][u] = h;
    out[((size_t)t * 64 + b) * 512 + d * 256 + u] = h;
    __syncthreads();   // hs[p^1] complete before next step reads it
    p ^= 1;
  }
  *cptr = c;
}

// ------------------------------------------------------- CRF loss + Viterbi
// grid=128, 64 thr: blocks 0..63 loss(batch b), 64..127 viterbi(batch b).
__global__ __launch_bounds__(64)
void crf_k(const float* __restrict__ em, const int* __restrict__ labels,
           const float* __restrict__ cs, const float* __restrict__ ce,
           const float* __restrict__ ct, float* __restrict__ dout) {
  __shared__ float trs[32 * 32];
  __shared__ float as_[32];
  __shared__ unsigned char bp[511 * 32];
  const int b = blockIdx.x & 63;
  const bool vit = blockIdx.x >= 64;
  const int lane = threadIdx.x;
  for (int i = lane; i < 1024; i += 64) trs[i] = ct[i];
  __syncthreads();
  const int j = lane & 31, half = lane >> 5, i0 = half * 16;

  if (!vit) {
    float part = 0.f;
    for (int tt = lane; tt < TLEN; tt += 64) {
      int lab = labels[b * TLEN + tt];
      part += em[((size_t)tt * 64 + b) * 32 + lab];
      if (tt) part += trs[labels[b * TLEN + tt - 1] * 32 + lab];
    }
    for (int o = 32; o > 0; o >>= 1) part += __shfl_down(part, o);
    float num = part;  // lane 0
    if (lane == 0) num += cs[labels[b * TLEN]] + ce[labels[b * TLEN + TLEN - 1]];
    if (lane < 32) as_[j] = cs[j] + em[(size_t)b * 32 + j];
    __syncthreads();
    for (int t = 1; t < TLEN; ++t) {
      float m = -1e30f;
      #pragma unroll
      for (int ii = 0; ii < 16; ++ii)
        m = fmaxf(m, as_[i0 + ii] + trs[(i0 + ii) * 32 + j]);
      float s = 0.f;
      #pragma unroll
      for (int ii = 0; ii < 16; ++ii)
        s += expf(as_[i0 + ii] + trs[(i0 + ii) * 32 + j] - m);
      float om = __shfl_xor(m, 32), os = __shfl_xor(s, 32);
      float M = fmaxf(m, om);
      s = s * expf(m - M) + os * expf(om - M);
      float na = M + logf(s) + em[((size_t)t * 64 + b) * 32 + j];
      __syncthreads();
      if (half == 0) as_[j] = na;
      __syncthreads();
    }
    float v = (lane < 32) ? as_[j] + ce[j] : -1e30f;
    float m = v;
    for (int o = 32; o > 0; o >>= 1) m = fmaxf(m, __shfl_xor(m, o));
    float s = (lane < 32) ? expf(v - m) : 0.f;
    for (int o = 32; o > 0; o >>= 1) s += __shfl_xor(s, o);
    if (lane == 0) atomicAdd(dout, -(num - (m + logf(s))));
  } else {
    if (lane < 32) as_[j] = cs[j] + em[(size_t)b * 32 + j];
    __syncthreads();
    for (int t = 1; t < TLEN; ++t) {
      float m = -1e30f; int am = 0;
      #pragma unroll
      for (int ii = 0; ii < 16; ++ii) {
        float v = as_[i0 + ii] + trs[(i0 + ii) * 32 + j];
        if (v > m) { m = v; am = i0 + ii; }
      }
      float om = __shfl_xor(m, 32); int oam = __shfl_xor(am, 32);
      float M; int AM;
      if (half == 0) { if (om > m) { M = om; AM = oam; } else { M = m; AM = am; } }
      else           { if (m > om) { M = m; AM = am; } else { M = om; AM = oam; } }
      float na = M + em[((size_t)t * 64 + b) * 32 + j];
      if (half == 0) bp[(t - 1) * 32 + j] = (unsigned char)AM;
      __syncthreads();
      if (half == 0) as_[j] = na;
      __syncthreads();
    }
    float v = (lane < 32) ? as_[j] + ce[j] : -1e30f;
    int aj = (lane < 32) ? j : 0;
    #pragma unroll
    for (int o = 1; o < 64; o <<= 1) {
      float ov = __shfl_xor(v, o); int oa = __shfl_xor(aj, o);
      if (ov > v || (ov == v && oa < aj)) { v = ov; aj = oa; }
    }
    if (lane == 0) {
      int cur = aj;
      dout[1 + b * TLEN + TLEN - 1] = (float)cur;
      for (int t = TLEN - 1; t >= 1; --t) {
        cur = bp[(t - 1) * 32 + cur];
        dout[1 + b * TLEN + t - 1] = (float)cur;
      }
    }
  }
}

// --------------------------------------------------------------------- launch
extern "C" void kernel_launch(void* const* d_in, const int* in_sizes, int n_in,
                              void* d_out, int out_size, void* d_ws, size_t ws_size,
                              hipStream_t stream) {
  (void)in_sizes; (void)n_in;
  float* dout = (float*)d_out;
  if (ws_size < WS_FLOATS * sizeof(float)) {  // diagnostic, not a fault
    ws_too_small_k<<<(out_size + 255) / 256, 256, 0, stream>>>(dout, out_size);
    return;
  }
  const int* ids    = (const int*)d_in[0];
  const int* labels = (const int*)d_in[1];
  const float* emb  = (const float*)d_in[3];
  const float* wih0f = (const float*)d_in[4],  *whh0f = (const float*)d_in[5],  *b0f = (const float*)d_in[6];
  const float* wih0b = (const float*)d_in[7],  *whh0b = (const float*)d_in[8],  *b0b = (const float*)d_in[9];
  const float* wih1f = (const float*)d_in[10], *whh1f = (const float*)d_in[11], *b1f = (const float*)d_in[12];
  const float* wih1b = (const float*)d_in[13], *whh1b = (const float*)d_in[14], *b1b = (const float*)d_in[15];
  const float* w_out = (const float*)d_in[16], *b_out = (const float*)d_in[17];
  const float* c_s = (const float*)d_in[18], *c_e = (const float*)d_in[19], *c_t = (const float*)d_in[20];
  float* ws   = (float*)d_ws;
  float* out0 = ws + O_OUT0;
  float* out1 = ws + O_OUT1;
  float* xg   = ws + O_XG;
  float* em   = ws + O_EM;    // aliases xg (xg dead once recurrences finish)
  float* wq   = ws + O_WQ;
  float* cst  = ws + O_CST;

  initz<<<1, 64, 0, stream>>>(dout);

  prep_w<<<512, 256, 0, stream>>>(whh0f, whh0b, wq);
  for (int k = 0; k < NCH; ++k) {
    gemm_k<256, 128, 0><<<dim3(32, 8, 2), 256, 0, stream>>>(
        emb, ids, wih0f, wih0b, b0f, b0b, xg, k * CS);
    lstm_bp<<<64, 512, 0, stream>>>(xg, wq, out0, cst, k * CS);
  }

  prep_w<<<512, 256, 0, stream>>>(whh1f, whh1b, wq);
  for (int k = 0; k < NCH; ++k) {
    gemm_k<512, 128, 1><<<dim3(32, 8, 2), 256, 0, stream>>>(
        out0, nullptr, wih1f, wih1b, b1f, b1b, xg, k * CS);
    lstm_bp<<<64, 512, 0, stream>>>(xg, wq, out1, cst + 32768, k * CS);
  }

  gemm_k<512, 32, 2><<<dim3(256, 1, 1), 256, 0, stream>>>(
      out1, nullptr, w_out, nullptr, b_out, nullptr, em, 0);
  crf_k<<<128, 64, 0, stream>>>(em, labels, c_s, c_e, c_t, dout);
}